// Round 4
// baseline (651.790 us; speedup 1.0000x reference)
//
#include <hip/hip_runtime.h>
#include <cstddef>

#define BB   8
#define NUU  1024
#define NII  2048
#define NTOT 3072
#define DD   64
#define KCAT 192

typedef __attribute__((ext_vector_type(8))) short bf16x8;
typedef __attribute__((ext_vector_type(4))) float f32x4;

__device__ __forceinline__ unsigned short f2bf(float f) {
  unsigned u = __float_as_uint(f);
  return (unsigned short)((u + 0x7fffu + ((u >> 16) & 1u)) >> 16);  // RNE
}
__device__ __forceinline__ float bf2f(unsigned short s) {
  return __uint_as_float(((unsigned)s) << 16);
}
__device__ __forceinline__ uint4 pack8(float4 a, float4 b) {
  uint4 r;
  r.x = (unsigned)f2bf(a.x) | ((unsigned)f2bf(a.y) << 16);
  r.y = (unsigned)f2bf(a.z) | ((unsigned)f2bf(a.w) << 16);
  r.z = (unsigned)f2bf(b.x) | ((unsigned)f2bf(b.y) << 16);
  r.w = (unsigned)f2bf(b.z) | ((unsigned)f2bf(b.w) << 16);
  return r;
}
__device__ __forceinline__ bf16x8 u4_to_bf(uint4 u) {
  union { uint4 a; bf16x8 b; } x; x.a = u; return x.b;
}

// ---- fused: gather tables -> ecat[:,:,0:64] bf16, transpose -> Et, plus
// one spare block (384) transposes the 4 weight matrices into wT ----
__global__ __launch_bounds__(256) void gather_t(
    const int* __restrict__ uidx, const int* __restrict__ iidx,
    const float* __restrict__ utab, const float* __restrict__ itab,
    const float* __restrict__ gcw, const float* __restrict__ biw,
    unsigned short* __restrict__ ecat, unsigned short* __restrict__ Et,
    float* __restrict__ wT) {
  const int tid = threadIdx.x;
  if (blockIdx.x >= 384) {  // weight transpose: wT[m][k*64+d] = W_m[d][k]
    for (int i = tid; i < 16384; i += 256) {
      int m = i >> 12, r = i & 4095;
      int k = r >> 6, d = r & 63;
      const float* src = (m < 2) ? gcw + m * 4096 : biw + (m - 2) * 4096;
      wT[i] = src[d * 64 + k];
    }
    return;
  }
  __shared__ unsigned short T[64][65];
  const int b = blockIdx.x / 48;
  const int r0 = (blockIdx.x % 48) * 64;
  {
    int nl = tid >> 2, f0 = (tid & 3) * 16;
    int row = r0 + nl;
    const float* src = (row < NUU) ? utab + (size_t)uidx[b * NUU + row] * DD
                                   : itab + (size_t)iidx[b * NII + row - NUU] * DD;
    const float4* s4 = reinterpret_cast<const float4*>(src + f0);
    uint4 lo = pack8(s4[0], s4[1]);
    uint4 hi = pack8(s4[2], s4[3]);
    uint4* dst = reinterpret_cast<uint4*>(ecat + ((size_t)b * NTOT + row) * KCAT + f0);
    dst[0] = lo; dst[1] = hi;
    unsigned short tmp[16];
    *reinterpret_cast<uint4*>(tmp) = lo;
    *reinterpret_cast<uint4*>(tmp + 8) = hi;
#pragma unroll
    for (int j = 0; j < 16; j++) T[f0 + j][nl] = tmp[j];
  }
  __syncthreads();
  {
    int f = tid >> 2, ng = (tid & 3) * 16;
    unsigned short tmp[16];
#pragma unroll
    for (int j = 0; j < 16; j++) tmp[j] = T[f][ng + j];
    uint4* dst = reinterpret_cast<uint4*>(
        Et + ((size_t)b * DD + f) * NTOT + r0 + ng);
    dst[0] = *reinterpret_cast<uint4*>(tmp);
    dst[1] = *reinterpret_cast<uint4*>(tmp + 8);
  }
}

// ---- transpose ecat[:, :, c0:c0+64] -> Et[b][64][3072] (feature-major) ----
__global__ __launch_bounds__(256) void conv_t(
    const unsigned short* __restrict__ ecat, int c0,
    unsigned short* __restrict__ Et) {
  __shared__ unsigned short T[64][65];
  const int tid = threadIdx.x;
  const int b = blockIdx.y;
  const int r0 = blockIdx.x * 64;
  {
    int nl = tid >> 2, fg = (tid & 3) * 16;
    const uint4* src = reinterpret_cast<const uint4*>(
        ecat + ((size_t)b * NTOT + r0 + nl) * KCAT + c0 + fg);
    uint4 v0 = src[0], v1 = src[1];
    unsigned short tmp[16];
    *reinterpret_cast<uint4*>(tmp) = v0;
    *reinterpret_cast<uint4*>(tmp + 8) = v1;
#pragma unroll
    for (int j = 0; j < 16; j++) T[fg + j][nl] = tmp[j];
  }
  __syncthreads();
  {
    int f = tid >> 2, ng = (tid & 3) * 16;
    unsigned short tmp[16];
#pragma unroll
    for (int j = 0; j < 16; j++) tmp[j] = T[f][ng + j];
    uint4* dst = reinterpret_cast<uint4*>(
        Et + ((size_t)b * DD + f) * NTOT + r0 + ng);
    dst[0] = *reinterpret_cast<uint4*>(tmp);
    dst[1] = *reinterpret_cast<uint4*>(tmp + 8);
  }
}

// ---- side partial = A[m,krange] @ E : MFMA, Et staged via LDS ----
// 128-row M-tile (2 strips/wave share B-fragments). Grid 24x4x8 = 3/CU.
// CONV=1: read adj fp32, convert (RNE) in-register, use + write adjb bf16.
// CONV=0: read adjb bf16. A register-prefetched one c-iter ahead.
template <int CONV>
__global__ __launch_bounds__(256) void side_mfma_t(
    const float* __restrict__ adj, unsigned short* __restrict__ adjb,
    const unsigned short* __restrict__ Et, float* __restrict__ sp) {
  __shared__ __align__(16) unsigned short Bs[2][64][68];
  const int tid = threadIdx.x;
  const int w = tid >> 6, l = tid & 63;
  const int lane15 = l & 15, quad = l >> 4;
  const int b = blockIdx.z, kz = blockIdx.y;
  const int m0 = blockIdx.x * 128 + w * 16;
  const int kbase = kz * 768;
  const size_t row0 = (size_t)b * NTOT * NTOT +
                      (size_t)(m0 + lane15) * NTOT + kbase + quad * 8;
  const size_t row1 = row0 + (size_t)64 * NTOT;
  const float* A32_0 = adj + row0;
  const float* A32_1 = adj + row1;
  const unsigned short* A16_0 = adjb + row0;
  const unsigned short* A16_1 = adjb + row1;
  unsigned short* Aw_0 = adjb + row0;
  unsigned short* Aw_1 = adjb + row1;

  const int sf = tid >> 3, ss = (tid & 7) * 8;
  const unsigned short* Eb = Et + (size_t)b * DD * NTOT + kbase;
  uint4 p0 = *reinterpret_cast<const uint4*>(Eb + (size_t)sf * NTOT + ss);
  uint4 p1 = *reinterpret_cast<const uint4*>(Eb + (size_t)(sf + 32) * NTOT + ss);

  bf16x8 a0_0, a1_0, a0_1, a1_1;
  float4 f0_0, f1_0, f2_0, f3_0, f0_1, f1_1, f2_1, f3_1;
  if (CONV) {
    f0_0 = *reinterpret_cast<const float4*>(A32_0 + 0);
    f1_0 = *reinterpret_cast<const float4*>(A32_0 + 4);
    f2_0 = *reinterpret_cast<const float4*>(A32_0 + 32);
    f3_0 = *reinterpret_cast<const float4*>(A32_0 + 36);
    f0_1 = *reinterpret_cast<const float4*>(A32_1 + 0);
    f1_1 = *reinterpret_cast<const float4*>(A32_1 + 4);
    f2_1 = *reinterpret_cast<const float4*>(A32_1 + 32);
    f3_1 = *reinterpret_cast<const float4*>(A32_1 + 36);
  } else {
    a0_0 = *reinterpret_cast<const bf16x8*>(A16_0);
    a1_0 = *reinterpret_cast<const bf16x8*>(A16_0 + 32);
    a0_1 = *reinterpret_cast<const bf16x8*>(A16_1);
    a1_1 = *reinterpret_cast<const bf16x8*>(A16_1 + 32);
  }

  f32x4 acc[2][4];
#pragma unroll
  for (int s = 0; s < 2; s++)
#pragma unroll
    for (int t = 0; t < 4; t++) acc[s][t] = (f32x4){0.f, 0.f, 0.f, 0.f};

  for (int c = 0; c < 12; c++) {
    const int buf = c & 1;
    __syncthreads();
    *reinterpret_cast<uint4*>(&Bs[buf][sf][ss]) = p0;
    *reinterpret_cast<uint4*>(&Bs[buf][sf + 32][ss]) = p1;
    __syncthreads();

    if (CONV) {
      uint4 u0 = pack8(f0_0, f1_0), u1 = pack8(f2_0, f3_0);
      *reinterpret_cast<uint4*>(Aw_0 + c * 64) = u0;
      *reinterpret_cast<uint4*>(Aw_0 + c * 64 + 32) = u1;
      a0_0 = u4_to_bf(u0);
      a1_0 = u4_to_bf(u1);
      uint4 u2 = pack8(f0_1, f1_1), u3 = pack8(f2_1, f3_1);
      *reinterpret_cast<uint4*>(Aw_1 + c * 64) = u2;
      *reinterpret_cast<uint4*>(Aw_1 + c * 64 + 32) = u3;
      a0_1 = u4_to_bf(u2);
      a1_1 = u4_to_bf(u3);
    }

    bf16x8 na0_0, na1_0, na0_1, na1_1;
    if (c + 1 < 12) {
      p0 = *reinterpret_cast<const uint4*>(Eb + (size_t)sf * NTOT + (c + 1) * 64 + ss);
      p1 = *reinterpret_cast<const uint4*>(Eb + (size_t)(sf + 32) * NTOT + (c + 1) * 64 + ss);
      if (CONV) {
        f0_0 = *reinterpret_cast<const float4*>(A32_0 + (c + 1) * 64);
        f1_0 = *reinterpret_cast<const float4*>(A32_0 + (c + 1) * 64 + 4);
        f2_0 = *reinterpret_cast<const float4*>(A32_0 + (c + 1) * 64 + 32);
        f3_0 = *reinterpret_cast<const float4*>(A32_0 + (c + 1) * 64 + 36);
        f0_1 = *reinterpret_cast<const float4*>(A32_1 + (c + 1) * 64);
        f1_1 = *reinterpret_cast<const float4*>(A32_1 + (c + 1) * 64 + 4);
        f2_1 = *reinterpret_cast<const float4*>(A32_1 + (c + 1) * 64 + 32);
        f3_1 = *reinterpret_cast<const float4*>(A32_1 + (c + 1) * 64 + 36);
      } else {
        na0_0 = *reinterpret_cast<const bf16x8*>(A16_0 + (c + 1) * 64);
        na1_0 = *reinterpret_cast<const bf16x8*>(A16_0 + (c + 1) * 64 + 32);
        na0_1 = *reinterpret_cast<const bf16x8*>(A16_1 + (c + 1) * 64);
        na1_1 = *reinterpret_cast<const bf16x8*>(A16_1 + (c + 1) * 64 + 32);
      }
    }

#pragma unroll
    for (int t = 0; t < 4; t++) {
      bf16x8 b0 = *reinterpret_cast<const bf16x8*>(&Bs[buf][t * 16 + lane15][quad * 8]);
      acc[0][t] = __builtin_amdgcn_mfma_f32_16x16x32_bf16(a0_0, b0, acc[0][t], 0, 0, 0);
      acc[1][t] = __builtin_amdgcn_mfma_f32_16x16x32_bf16(a0_1, b0, acc[1][t], 0, 0, 0);
    }
#pragma unroll
    for (int t = 0; t < 4; t++) {
      bf16x8 b1 = *reinterpret_cast<const bf16x8*>(&Bs[buf][t * 16 + lane15][32 + quad * 8]);
      acc[0][t] = __builtin_amdgcn_mfma_f32_16x16x32_bf16(a1_0, b1, acc[0][t], 0, 0, 0);
      acc[1][t] = __builtin_amdgcn_mfma_f32_16x16x32_bf16(a1_1, b1, acc[1][t], 0, 0, 0);
    }
    if (!CONV && (c + 1 < 12)) {
      a0_0 = na0_0; a1_0 = na1_0; a0_1 = na0_1; a1_1 = na1_1;
    }
  }

  float* S = sp + ((size_t)kz * BB + b) * ((size_t)NTOT * DD);
#pragma unroll
  for (int s = 0; s < 2; s++)
#pragma unroll
    for (int t = 0; t < 4; t++)
#pragma unroll
      for (int r = 0; r < 4; r++)
        S[(size_t)(m0 + s * 64 + quad * 4 + r) * DD + t * 16 + lane15] =
            acc[s][t][r];
}

// ---- ego_out = lrelu(side@gcW^T+gcb) + lrelu((ego*side)@biW^T+bib), bf16 io ----
__global__ __launch_bounds__(256) void layer_post(
    const float* __restrict__ sp, unsigned short* __restrict__ ecat, int cin,
    const float* __restrict__ wTg, const float* __restrict__ wTb,
    const float* __restrict__ gcb, const float* __restrict__ bib) {
  __shared__ float wG[4096];
  __shared__ float wB[4096];
  __shared__ float rowS[4][64];
  __shared__ float rowE[4][64];
  const int tid = threadIdx.x;
#pragma unroll
  for (int i = 0; i < 16; i++) {
    int idx = tid + i * 256;
    wG[idx] = wTg[idx];   // already [k][d]
    wB[idx] = wTb[idx];
  }
  const int wv = tid >> 6, lane = tid & 63;
  const size_t row = (size_t)blockIdx.x * 4 + wv;
  const size_t off = row * DD + lane;
  const size_t P = (size_t)BB * NTOT * DD;
  float sv = sp[off] + sp[P + off] + sp[2 * P + off] + sp[3 * P + off];
  float ev = bf2f(ecat[row * KCAT + cin + lane]);
  rowS[wv][lane] = sv;
  rowE[wv][lane] = ev;
  __syncthreads();
  float sacc = gcb[lane];
  float bacc = bib[lane];
#pragma unroll 8
  for (int k = 0; k < 64; k++) {
    float sk = rowS[wv][k];
    float ek = rowE[wv][k];
    sacc += sk * wG[k * 64 + lane];
    bacc += (ek * sk) * wB[k * 64 + lane];
  }
  float s  = sacc > 0.f ? sacc : 0.01f * sacc;
  float bi = bacc > 0.f ? bacc : 0.01f * bacc;
  ecat[row * KCAT + cin + 64 + lane] = f2bf(s + bi);
}

// ---- fused scores + log_softmax: block = 16 u-rows x all 2048 items ----
// S[16][2048] fp32 = 128 KB LDS; U frags in regs; I frags streamed from
// L2-hot ecat with register prefetch; row reduce + single normalized write.
__global__ __launch_bounds__(256) void scores_lsm(
    const unsigned short* __restrict__ ecat, float* __restrict__ out) {
  __shared__ float S[16][NII];   // 128 KB
  const int tid = threadIdx.x;
  const int w = tid >> 6, l = tid & 63;
  const int lane15 = l & 15, quad = l >> 4;
  const int b = blockIdx.y;
  const int u0 = blockIdx.x * 16;

  // U fragments: 16 u-rows, full K=192 (6 slices) — identical in all waves
  bf16x8 af[6];
  const unsigned short* U =
      ecat + ((size_t)b * NTOT + u0 + lane15) * KCAT + quad * 8;
#pragma unroll
  for (int ks = 0; ks < 6; ks++)
    af[ks] = *reinterpret_cast<const bf16x8*>(U + ks * 32);

  const unsigned short* I =
      ecat + ((size_t)b * NTOT + NUU) * KCAT + quad * 8;
  bf16x8 cur[6], nxt[6];
  {
    const unsigned short* Ir = I + (size_t)(w * 16 + lane15) * KCAT;
#pragma unroll
    for (int ks = 0; ks < 6; ks++)
      cur[ks] = *reinterpret_cast<const bf16x8*>(Ir + ks * 32);
  }
  for (int ch = 0; ch < 32; ch++) {
    if (ch + 1 < 32) {
      const unsigned short* Ir =
          I + (size_t)((ch + 1) * 64 + w * 16 + lane15) * KCAT;
#pragma unroll
      for (int ks = 0; ks < 6; ks++)
        nxt[ks] = *reinterpret_cast<const bf16x8*>(Ir + ks * 32);
    }
    f32x4 acc = (f32x4){0.f, 0.f, 0.f, 0.f};
#pragma unroll
    for (int ks = 0; ks < 6; ks++)
      acc = __builtin_amdgcn_mfma_f32_16x16x32_bf16(af[ks], cur[ks], acc, 0, 0, 0);
    const int ic = ch * 64 + w * 16 + lane15;
#pragma unroll
    for (int r = 0; r < 4; r++) S[quad * 4 + r][ic] = acc[r];
#pragma unroll
    for (int ks = 0; ks < 6; ks++) cur[ks] = nxt[ks];
  }
  __syncthreads();
  // wave w reduces + writes rows w*4 .. w*4+3
  for (int rr = 0; rr < 4; rr++) {
    const int row = w * 4 + rr;
    float v[32];
    float m = -3.4e38f;
#pragma unroll
    for (int j = 0; j < 32; j++) {
      v[j] = S[row][j * 64 + l];
      m = fmaxf(m, v[j]);
    }
#pragma unroll
    for (int off = 32; off > 0; off >>= 1) m = fmaxf(m, __shfl_xor(m, off));
    float s = 0.f;
#pragma unroll
    for (int j = 0; j < 32; j++) s += expf(v[j] - m);
#pragma unroll
    for (int off = 32; off > 0; off >>= 1) s += __shfl_xor(s, off);
    const float lse = m + logf(s);
    float* orow = out + ((size_t)b * NUU + u0 + row) * NII;
#pragma unroll
    for (int j = 0; j < 8; j++) {
      float4 q = *reinterpret_cast<const float4*>(&S[row][j * 256 + l * 4]);
      q.x -= lse; q.y -= lse; q.z -= lse; q.w -= lse;
      *reinterpret_cast<float4*>(orow + j * 256 + l * 4) = q;
    }
  }
}

extern "C" void kernel_launch(void* const* d_in, const int* in_sizes, int n_in,
                              void* d_out, int out_size, void* d_ws, size_t ws_size,
                              hipStream_t stream) {
  (void)in_sizes; (void)n_in; (void)out_size; (void)ws_size;
  const int*   uidx = (const int*)d_in[0];
  const int*   iidx = (const int*)d_in[1];
  const float* adj  = (const float*)d_in[2];
  const float* utab = (const float*)d_in[3];
  const float* itab = (const float*)d_in[4];
  const float* gcw  = (const float*)d_in[5];
  const float* gcb  = (const float*)d_in[6];
  const float* biw  = (const float*)d_in[7];
  const float* bib  = (const float*)d_in[8];
  float* out = (float*)d_out;

  // ws layout: ecat bf16 [B][3072][192] (9.4MB) | Et bf16 [B][64][3072] (3.1MB)
  //          | adjb bf16 [B][3072][3072] (151MB, written by side_mfma_t<1>)
  unsigned short* ecat = (unsigned short*)d_ws;
  unsigned short* Et   = ecat + (size_t)BB * NTOT * KCAT;
  unsigned short* adjb = Et + (size_t)BB * DD * NTOT;
  // d_out scratch: sp = 4 K-split fp32 partials [4][B][3072][64] (25.2MB),
  // then wT = transposed weights [4][64][64] (64KB). Both consumed by
  // layer_post before scores_lsm overwrites d_out.
  float* sp = (float*)d_out;
  const size_t P = (size_t)BB * NTOT * DD;
  float* wT = (float*)d_out + 4 * P;

  gather_t<<<dim3(385), 256, 0, stream>>>(uidx, iidx, utab, itab, gcw, biw, ecat, Et, wT);
  side_mfma_t<1><<<dim3(24, 4, BB), 256, 0, stream>>>(adj, adjb, Et, sp);
  layer_post<<<dim3(BB * NTOT / 4), 256, 0, stream>>>(sp, ecat, 0, wT, wT + 2 * 4096, gcb, bib);
  conv_t<<<dim3(48, BB), 256, 0, stream>>>(ecat, 64, Et);
  side_mfma_t<0><<<dim3(24, 4, BB), 256, 0, stream>>>(adj, adjb, Et, sp);
  layer_post<<<dim3(BB * NTOT / 4), 256, 0, stream>>>(sp, ecat, 64, wT + 4096, wT + 3 * 4096, gcb + 64, bib + 64);
  scores_lsm<<<dim3(64, BB), 256, 0, stream>>>(ecat, out);
}

// Round 5
// 647.775 us; speedup vs baseline: 1.0062x; 1.0062x over previous
//
#include <hip/hip_runtime.h>
#include <cstddef>

#define BB   8
#define NUU  1024
#define NII  2048
#define NTOT 3072
#define DD   64
#define KCAT 192

typedef __attribute__((ext_vector_type(8))) short bf16x8;
typedef __attribute__((ext_vector_type(4))) float f32x4;

__device__ __forceinline__ unsigned short f2bf(float f) {
  unsigned u = __float_as_uint(f);
  return (unsigned short)((u + 0x7fffu + ((u >> 16) & 1u)) >> 16);  // RNE
}
__device__ __forceinline__ float bf2f(unsigned short s) {
  return __uint_as_float(((unsigned)s) << 16);
}
__device__ __forceinline__ uint4 pack8(float4 a, float4 b) {
  uint4 r;
  r.x = (unsigned)f2bf(a.x) | ((unsigned)f2bf(a.y) << 16);
  r.y = (unsigned)f2bf(a.z) | ((unsigned)f2bf(a.w) << 16);
  r.z = (unsigned)f2bf(b.x) | ((unsigned)f2bf(b.y) << 16);
  r.w = (unsigned)f2bf(b.z) | ((unsigned)f2bf(b.w) << 16);
  return r;
}
__device__ __forceinline__ bf16x8 u4_to_bf(uint4 u) {
  union { uint4 a; bf16x8 b; } x; x.a = u; return x.b;
}

// ---- fused: gather tables -> ecat[:,:,0:64] bf16, transpose -> Et, plus
// one spare block (384) transposes the 4 weight matrices into wT ----
__global__ __launch_bounds__(256) void gather_t(
    const int* __restrict__ uidx, const int* __restrict__ iidx,
    const float* __restrict__ utab, const float* __restrict__ itab,
    const float* __restrict__ gcw, const float* __restrict__ biw,
    unsigned short* __restrict__ ecat, unsigned short* __restrict__ Et,
    float* __restrict__ wT) {
  const int tid = threadIdx.x;
  if (blockIdx.x >= 384) {  // weight transpose: wT[m][k*64+d] = W_m[d][k]
    for (int i = tid; i < 16384; i += 256) {
      int m = i >> 12, r = i & 4095;
      int k = r >> 6, d = r & 63;
      const float* src = (m < 2) ? gcw + m * 4096 : biw + (m - 2) * 4096;
      wT[i] = src[d * 64 + k];
    }
    return;
  }
  __shared__ unsigned short T[64][65];
  const int b = blockIdx.x / 48;
  const int r0 = (blockIdx.x % 48) * 64;
  {
    int nl = tid >> 2, f0 = (tid & 3) * 16;
    int row = r0 + nl;
    const float* src = (row < NUU) ? utab + (size_t)uidx[b * NUU + row] * DD
                                   : itab + (size_t)iidx[b * NII + row - NUU] * DD;
    const float4* s4 = reinterpret_cast<const float4*>(src + f0);
    uint4 lo = pack8(s4[0], s4[1]);
    uint4 hi = pack8(s4[2], s4[3]);
    uint4* dst = reinterpret_cast<uint4*>(ecat + ((size_t)b * NTOT + row) * KCAT + f0);
    dst[0] = lo; dst[1] = hi;
    unsigned short tmp[16];
    *reinterpret_cast<uint4*>(tmp) = lo;
    *reinterpret_cast<uint4*>(tmp + 8) = hi;
#pragma unroll
    for (int j = 0; j < 16; j++) T[f0 + j][nl] = tmp[j];
  }
  __syncthreads();
  {
    int f = tid >> 2, ng = (tid & 3) * 16;
    unsigned short tmp[16];
#pragma unroll
    for (int j = 0; j < 16; j++) tmp[j] = T[f][ng + j];
    uint4* dst = reinterpret_cast<uint4*>(
        Et + ((size_t)b * DD + f) * NTOT + r0 + ng);
    dst[0] = *reinterpret_cast<uint4*>(tmp);
    dst[1] = *reinterpret_cast<uint4*>(tmp + 8);
  }
}

// ---- transpose ecat[:, :, c0:c0+64] -> Et[b][64][3072] (feature-major) ----
__global__ __launch_bounds__(256) void conv_t(
    const unsigned short* __restrict__ ecat, int c0,
    unsigned short* __restrict__ Et) {
  __shared__ unsigned short T[64][65];
  const int tid = threadIdx.x;
  const int b = blockIdx.y;
  const int r0 = blockIdx.x * 64;
  {
    int nl = tid >> 2, fg = (tid & 3) * 16;
    const uint4* src = reinterpret_cast<const uint4*>(
        ecat + ((size_t)b * NTOT + r0 + nl) * KCAT + c0 + fg);
    uint4 v0 = src[0], v1 = src[1];
    unsigned short tmp[16];
    *reinterpret_cast<uint4*>(tmp) = v0;
    *reinterpret_cast<uint4*>(tmp + 8) = v1;
#pragma unroll
    for (int j = 0; j < 16; j++) T[fg + j][nl] = tmp[j];
  }
  __syncthreads();
  {
    int f = tid >> 2, ng = (tid & 3) * 16;
    unsigned short tmp[16];
#pragma unroll
    for (int j = 0; j < 16; j++) tmp[j] = T[f][ng + j];
    uint4* dst = reinterpret_cast<uint4*>(
        Et + ((size_t)b * DD + f) * NTOT + r0 + ng);
    dst[0] = *reinterpret_cast<uint4*>(tmp);
    dst[1] = *reinterpret_cast<uint4*>(tmp + 8);
  }
}

// ---- side partial = A[m,krange] @ E : MFMA, Et staged via LDS ----
// 128-row M-tile (2 strips/wave share B-fragments). Grid 24x4x8 = 3/CU.
// CONV=1: read adj fp32, convert (RNE) in-register, use + write adjb bf16.
// CONV=0: read adjb bf16. A register-prefetched one c-iter ahead.
template <int CONV>
__global__ __launch_bounds__(256) void side_mfma_t(
    const float* __restrict__ adj, unsigned short* __restrict__ adjb,
    const unsigned short* __restrict__ Et, float* __restrict__ sp) {
  __shared__ __align__(16) unsigned short Bs[2][64][68];
  const int tid = threadIdx.x;
  const int w = tid >> 6, l = tid & 63;
  const int lane15 = l & 15, quad = l >> 4;
  const int b = blockIdx.z, kz = blockIdx.y;
  const int m0 = blockIdx.x * 128 + w * 16;
  const int kbase = kz * 768;
  const size_t row0 = (size_t)b * NTOT * NTOT +
                      (size_t)(m0 + lane15) * NTOT + kbase + quad * 8;
  const size_t row1 = row0 + (size_t)64 * NTOT;
  const float* A32_0 = adj + row0;
  const float* A32_1 = adj + row1;
  const unsigned short* A16_0 = adjb + row0;
  const unsigned short* A16_1 = adjb + row1;
  unsigned short* Aw_0 = adjb + row0;
  unsigned short* Aw_1 = adjb + row1;

  const int sf = tid >> 3, ss = (tid & 7) * 8;
  const unsigned short* Eb = Et + (size_t)b * DD * NTOT + kbase;
  uint4 p0 = *reinterpret_cast<const uint4*>(Eb + (size_t)sf * NTOT + ss);
  uint4 p1 = *reinterpret_cast<const uint4*>(Eb + (size_t)(sf + 32) * NTOT + ss);

  bf16x8 a0_0, a1_0, a0_1, a1_1;
  float4 f0_0, f1_0, f2_0, f3_0, f0_1, f1_1, f2_1, f3_1;
  if (CONV) {
    f0_0 = *reinterpret_cast<const float4*>(A32_0 + 0);
    f1_0 = *reinterpret_cast<const float4*>(A32_0 + 4);
    f2_0 = *reinterpret_cast<const float4*>(A32_0 + 32);
    f3_0 = *reinterpret_cast<const float4*>(A32_0 + 36);
    f0_1 = *reinterpret_cast<const float4*>(A32_1 + 0);
    f1_1 = *reinterpret_cast<const float4*>(A32_1 + 4);
    f2_1 = *reinterpret_cast<const float4*>(A32_1 + 32);
    f3_1 = *reinterpret_cast<const float4*>(A32_1 + 36);
  } else {
    a0_0 = *reinterpret_cast<const bf16x8*>(A16_0);
    a1_0 = *reinterpret_cast<const bf16x8*>(A16_0 + 32);
    a0_1 = *reinterpret_cast<const bf16x8*>(A16_1);
    a1_1 = *reinterpret_cast<const bf16x8*>(A16_1 + 32);
  }

  f32x4 acc[2][4];
#pragma unroll
  for (int s = 0; s < 2; s++)
#pragma unroll
    for (int t = 0; t < 4; t++) acc[s][t] = (f32x4){0.f, 0.f, 0.f, 0.f};

  for (int c = 0; c < 12; c++) {
    const int buf = c & 1;
    __syncthreads();
    *reinterpret_cast<uint4*>(&Bs[buf][sf][ss]) = p0;
    *reinterpret_cast<uint4*>(&Bs[buf][sf + 32][ss]) = p1;
    __syncthreads();

    if (CONV) {
      uint4 u0 = pack8(f0_0, f1_0), u1 = pack8(f2_0, f3_0);
      *reinterpret_cast<uint4*>(Aw_0 + c * 64) = u0;
      *reinterpret_cast<uint4*>(Aw_0 + c * 64 + 32) = u1;
      a0_0 = u4_to_bf(u0);
      a1_0 = u4_to_bf(u1);
      uint4 u2 = pack8(f0_1, f1_1), u3 = pack8(f2_1, f3_1);
      *reinterpret_cast<uint4*>(Aw_1 + c * 64) = u2;
      *reinterpret_cast<uint4*>(Aw_1 + c * 64 + 32) = u3;
      a0_1 = u4_to_bf(u2);
      a1_1 = u4_to_bf(u3);
    }

    bf16x8 na0_0, na1_0, na0_1, na1_1;
    if (c + 1 < 12) {
      p0 = *reinterpret_cast<const uint4*>(Eb + (size_t)sf * NTOT + (c + 1) * 64 + ss);
      p1 = *reinterpret_cast<const uint4*>(Eb + (size_t)(sf + 32) * NTOT + (c + 1) * 64 + ss);
      if (CONV) {
        f0_0 = *reinterpret_cast<const float4*>(A32_0 + (c + 1) * 64);
        f1_0 = *reinterpret_cast<const float4*>(A32_0 + (c + 1) * 64 + 4);
        f2_0 = *reinterpret_cast<const float4*>(A32_0 + (c + 1) * 64 + 32);
        f3_0 = *reinterpret_cast<const float4*>(A32_0 + (c + 1) * 64 + 36);
        f0_1 = *reinterpret_cast<const float4*>(A32_1 + (c + 1) * 64);
        f1_1 = *reinterpret_cast<const float4*>(A32_1 + (c + 1) * 64 + 4);
        f2_1 = *reinterpret_cast<const float4*>(A32_1 + (c + 1) * 64 + 32);
        f3_1 = *reinterpret_cast<const float4*>(A32_1 + (c + 1) * 64 + 36);
      } else {
        na0_0 = *reinterpret_cast<const bf16x8*>(A16_0 + (c + 1) * 64);
        na1_0 = *reinterpret_cast<const bf16x8*>(A16_0 + (c + 1) * 64 + 32);
        na0_1 = *reinterpret_cast<const bf16x8*>(A16_1 + (c + 1) * 64);
        na1_1 = *reinterpret_cast<const bf16x8*>(A16_1 + (c + 1) * 64 + 32);
      }
    }

#pragma unroll
    for (int t = 0; t < 4; t++) {
      bf16x8 b0 = *reinterpret_cast<const bf16x8*>(&Bs[buf][t * 16 + lane15][quad * 8]);
      acc[0][t] = __builtin_amdgcn_mfma_f32_16x16x32_bf16(a0_0, b0, acc[0][t], 0, 0, 0);
      acc[1][t] = __builtin_amdgcn_mfma_f32_16x16x32_bf16(a0_1, b0, acc[1][t], 0, 0, 0);
    }
#pragma unroll
    for (int t = 0; t < 4; t++) {
      bf16x8 b1 = *reinterpret_cast<const bf16x8*>(&Bs[buf][t * 16 + lane15][32 + quad * 8]);
      acc[0][t] = __builtin_amdgcn_mfma_f32_16x16x32_bf16(a1_0, b1, acc[0][t], 0, 0, 0);
      acc[1][t] = __builtin_amdgcn_mfma_f32_16x16x32_bf16(a1_1, b1, acc[1][t], 0, 0, 0);
    }
    if (!CONV && (c + 1 < 12)) {
      a0_0 = na0_0; a1_0 = na1_0; a0_1 = na0_1; a1_1 = na1_1;
    }
  }

  float* S = sp + ((size_t)kz * BB + b) * ((size_t)NTOT * DD);
#pragma unroll
  for (int s = 0; s < 2; s++)
#pragma unroll
    for (int t = 0; t < 4; t++)
#pragma unroll
      for (int r = 0; r < 4; r++)
        S[(size_t)(m0 + s * 64 + quad * 4 + r) * DD + t * 16 + lane15] =
            acc[s][t][r];
}

// ---- ego_out = lrelu(side@gcW^T+gcb) + lrelu((ego*side)@biW^T+bib), bf16 io ----
__global__ __launch_bounds__(256) void layer_post(
    const float* __restrict__ sp, unsigned short* __restrict__ ecat, int cin,
    const float* __restrict__ wTg, const float* __restrict__ wTb,
    const float* __restrict__ gcb, const float* __restrict__ bib) {
  __shared__ float wG[4096];
  __shared__ float wB[4096];
  __shared__ float rowS[4][64];
  __shared__ float rowE[4][64];
  const int tid = threadIdx.x;
#pragma unroll
  for (int i = 0; i < 16; i++) {
    int idx = tid + i * 256;
    wG[idx] = wTg[idx];   // already [k][d]
    wB[idx] = wTb[idx];
  }
  const int wv = tid >> 6, lane = tid & 63;
  const size_t row = (size_t)blockIdx.x * 4 + wv;
  const size_t off = row * DD + lane;
  const size_t P = (size_t)BB * NTOT * DD;
  float sv = sp[off] + sp[P + off] + sp[2 * P + off] + sp[3 * P + off];
  float ev = bf2f(ecat[row * KCAT + cin + lane]);
  rowS[wv][lane] = sv;
  rowE[wv][lane] = ev;
  __syncthreads();
  float sacc = gcb[lane];
  float bacc = bib[lane];
#pragma unroll 8
  for (int k = 0; k < 64; k++) {
    float sk = rowS[wv][k];
    float ek = rowE[wv][k];
    sacc += sk * wG[k * 64 + lane];
    bacc += (ek * sk) * wB[k * 64 + lane];
  }
  float s  = sacc > 0.f ? sacc : 0.01f * sacc;
  float bi = bacc > 0.f ? bacc : 0.01f * bacc;
  ecat[row * KCAT + cin + 64 + lane] = f2bf(s + bi);
}

// ---- fused scores + log_softmax: block = 16 u-rows x all 2048 items ----
// 512 threads (8 waves -> 2 waves/SIMD for latency hiding; 128KB LDS caps
// at 1 block/CU). S[16][2048] fp32 in LDS; U frags in regs; I frags
// streamed from L2-hot ecat with register prefetch. Reduce phase keeps the
// row in registers and writes normalized values directly (no LDS re-read).
__global__ __launch_bounds__(512) void scores_lsm(
    const unsigned short* __restrict__ ecat, float* __restrict__ out) {
  __shared__ float S[16][NII];   // 128 KB
  const int tid = threadIdx.x;
  const int w = tid >> 6, l = tid & 63;
  const int lane15 = l & 15, quad = l >> 4;
  const int b = blockIdx.y;
  const int u0 = blockIdx.x * 16;

  // U fragments: 16 u-rows, full K=192 (6 slices) — identical in all waves
  bf16x8 af[6];
  const unsigned short* U =
      ecat + ((size_t)b * NTOT + u0 + lane15) * KCAT + quad * 8;
#pragma unroll
  for (int ks = 0; ks < 6; ks++)
    af[ks] = *reinterpret_cast<const bf16x8*>(U + ks * 32);

  const unsigned short* I =
      ecat + ((size_t)b * NTOT + NUU) * KCAT + quad * 8;
  bf16x8 cur[6], nxt[6];
  {
    const unsigned short* Ir = I + (size_t)(w * 16 + lane15) * KCAT;
#pragma unroll
    for (int ks = 0; ks < 6; ks++)
      cur[ks] = *reinterpret_cast<const bf16x8*>(Ir + ks * 32);
  }
  // 16 chunks of 128 items; wave w owns items ch*128 + w*16 .. +15
  for (int ch = 0; ch < 16; ch++) {
    if (ch + 1 < 16) {
      const unsigned short* Ir =
          I + (size_t)((ch + 1) * 128 + w * 16 + lane15) * KCAT;
#pragma unroll
      for (int ks = 0; ks < 6; ks++)
        nxt[ks] = *reinterpret_cast<const bf16x8*>(Ir + ks * 32);
    }
    f32x4 acc = (f32x4){0.f, 0.f, 0.f, 0.f};
#pragma unroll
    for (int ks = 0; ks < 6; ks++)
      acc = __builtin_amdgcn_mfma_f32_16x16x32_bf16(af[ks], cur[ks], acc, 0, 0, 0);
    const int ic = ch * 128 + w * 16 + lane15;
#pragma unroll
    for (int r = 0; r < 4; r++) S[quad * 4 + r][ic] = acc[r];
#pragma unroll
    for (int ks = 0; ks < 6; ks++) cur[ks] = nxt[ks];
  }
  __syncthreads();
  // wave w reduces + writes rows w*2, w*2+1 — values stay in registers
  for (int rr = 0; rr < 2; rr++) {
    const int row = w * 2 + rr;
    float v[32];
    float m = -3.4e38f;
#pragma unroll
    for (int j = 0; j < 32; j++) {
      v[j] = S[row][j * 64 + l];
      m = fmaxf(m, v[j]);
    }
#pragma unroll
    for (int off = 32; off > 0; off >>= 1) m = fmaxf(m, __shfl_xor(m, off));
    float s = 0.f;
#pragma unroll
    for (int j = 0; j < 32; j++) s += expf(v[j] - m);
#pragma unroll
    for (int off = 32; off > 0; off >>= 1) s += __shfl_xor(s, off);
    const float lse = m + logf(s);
    float* orow = out + ((size_t)b * NUU + u0 + row) * NII;
#pragma unroll
    for (int j = 0; j < 32; j++) orow[j * 64 + l] = v[j] - lse;
  }
}

extern "C" void kernel_launch(void* const* d_in, const int* in_sizes, int n_in,
                              void* d_out, int out_size, void* d_ws, size_t ws_size,
                              hipStream_t stream) {
  (void)in_sizes; (void)n_in; (void)out_size; (void)ws_size;
  const int*   uidx = (const int*)d_in[0];
  const int*   iidx = (const int*)d_in[1];
  const float* adj  = (const float*)d_in[2];
  const float* utab = (const float*)d_in[3];
  const float* itab = (const float*)d_in[4];
  const float* gcw  = (const float*)d_in[5];
  const float* gcb  = (const float*)d_in[6];
  const float* biw  = (const float*)d_in[7];
  const float* bib  = (const float*)d_in[8];
  float* out = (float*)d_out;

  // ws layout: ecat bf16 [B][3072][192] (9.4MB) | Et bf16 [B][64][3072] (3.1MB)
  //          | adjb bf16 [B][3072][3072] (151MB, written by side_mfma_t<1>)
  unsigned short* ecat = (unsigned short*)d_ws;
  unsigned short* Et   = ecat + (size_t)BB * NTOT * KCAT;
  unsigned short* adjb = Et + (size_t)BB * DD * NTOT;
  // d_out scratch: sp = 4 K-split fp32 partials [4][B][3072][64] (25.2MB),
  // then wT = transposed weights [4][64][64] (64KB). Both consumed by
  // layer_post before scores_lsm overwrites d_out.
  float* sp = (float*)d_out;
  const size_t P = (size_t)BB * NTOT * DD;
  float* wT = (float*)d_out + 4 * P;

  gather_t<<<dim3(385), 256, 0, stream>>>(uidx, iidx, utab, itab, gcw, biw, ecat, Et, wT);
  side_mfma_t<1><<<dim3(24, 4, BB), 256, 0, stream>>>(adj, adjb, Et, sp);
  layer_post<<<dim3(BB * NTOT / 4), 256, 0, stream>>>(sp, ecat, 0, wT, wT + 2 * 4096, gcb, bib);
  conv_t<<<dim3(48, BB), 256, 0, stream>>>(ecat, 64, Et);
  side_mfma_t<0><<<dim3(24, 4, BB), 256, 0, stream>>>(adj, adjb, Et, sp);
  layer_post<<<dim3(BB * NTOT / 4), 256, 0, stream>>>(sp, ecat, 64, wT + 4096, wT + 3 * 4096, gcb + 64, bib + 64);
  scores_lsm<<<dim3(64, BB), 512, 0, stream>>>(ecat, out);
}

// Round 6
// 605.051 us; speedup vs baseline: 1.0772x; 1.0706x over previous
//
#include <hip/hip_runtime.h>
#include <cstddef>

#define BB   8
#define NUU  1024
#define NII  2048
#define NTOT 3072
#define DD   64
#define KCAT 192

typedef __attribute__((ext_vector_type(8))) short bf16x8;
typedef __attribute__((ext_vector_type(4))) float f32x4;

__device__ __forceinline__ unsigned short f2bf(float f) {
  unsigned u = __float_as_uint(f);
  return (unsigned short)((u + 0x7fffu + ((u >> 16) & 1u)) >> 16);  // RNE
}
__device__ __forceinline__ float bf2f(unsigned short s) {
  return __uint_as_float(((unsigned)s) << 16);
}
__device__ __forceinline__ uint4 pack8(float4 a, float4 b) {
  uint4 r;
  r.x = (unsigned)f2bf(a.x) | ((unsigned)f2bf(a.y) << 16);
  r.y = (unsigned)f2bf(a.z) | ((unsigned)f2bf(a.w) << 16);
  r.z = (unsigned)f2bf(b.x) | ((unsigned)f2bf(b.y) << 16);
  r.w = (unsigned)f2bf(b.z) | ((unsigned)f2bf(b.w) << 16);
  return r;
}
__device__ __forceinline__ bf16x8 u4_to_bf(uint4 u) {
  union { uint4 a; bf16x8 b; } x; x.a = u; return x.b;
}

// ---- fused: gather tables -> ecat[:,:,0:64] bf16, transpose -> Et, plus
// one spare block (384) transposes the 4 weight matrices into wT ----
__global__ __launch_bounds__(256) void gather_t(
    const int* __restrict__ uidx, const int* __restrict__ iidx,
    const float* __restrict__ utab, const float* __restrict__ itab,
    const float* __restrict__ gcw, const float* __restrict__ biw,
    unsigned short* __restrict__ ecat, unsigned short* __restrict__ Et,
    float* __restrict__ wT) {
  const int tid = threadIdx.x;
  if (blockIdx.x >= 384) {  // weight transpose: wT[m][k*64+d] = W_m[d][k]
    for (int i = tid; i < 16384; i += 256) {
      int m = i >> 12, r = i & 4095;
      int k = r >> 6, d = r & 63;
      const float* src = (m < 2) ? gcw + m * 4096 : biw + (m - 2) * 4096;
      wT[i] = src[d * 64 + k];
    }
    return;
  }
  __shared__ unsigned short T[64][65];
  const int b = blockIdx.x / 48;
  const int r0 = (blockIdx.x % 48) * 64;
  {
    int nl = tid >> 2, f0 = (tid & 3) * 16;
    int row = r0 + nl;
    const float* src = (row < NUU) ? utab + (size_t)uidx[b * NUU + row] * DD
                                   : itab + (size_t)iidx[b * NII + row - NUU] * DD;
    const float4* s4 = reinterpret_cast<const float4*>(src + f0);
    uint4 lo = pack8(s4[0], s4[1]);
    uint4 hi = pack8(s4[2], s4[3]);
    uint4* dst = reinterpret_cast<uint4*>(ecat + ((size_t)b * NTOT + row) * KCAT + f0);
    dst[0] = lo; dst[1] = hi;
    unsigned short tmp[16];
    *reinterpret_cast<uint4*>(tmp) = lo;
    *reinterpret_cast<uint4*>(tmp + 8) = hi;
#pragma unroll
    for (int j = 0; j < 16; j++) T[f0 + j][nl] = tmp[j];
  }
  __syncthreads();
  {
    int f = tid >> 2, ng = (tid & 3) * 16;
    unsigned short tmp[16];
#pragma unroll
    for (int j = 0; j < 16; j++) tmp[j] = T[f][ng + j];
    uint4* dst = reinterpret_cast<uint4*>(
        Et + ((size_t)b * DD + f) * NTOT + r0 + ng);
    dst[0] = *reinterpret_cast<uint4*>(tmp);
    dst[1] = *reinterpret_cast<uint4*>(tmp + 8);
  }
}

// ---- transpose ecat[:, :, c0:c0+64] -> Et[b][64][3072] (feature-major) ----
__global__ __launch_bounds__(256) void conv_t(
    const unsigned short* __restrict__ ecat, int c0,
    unsigned short* __restrict__ Et) {
  __shared__ unsigned short T[64][65];
  const int tid = threadIdx.x;
  const int b = blockIdx.y;
  const int r0 = blockIdx.x * 64;
  {
    int nl = tid >> 2, fg = (tid & 3) * 16;
    const uint4* src = reinterpret_cast<const uint4*>(
        ecat + ((size_t)b * NTOT + r0 + nl) * KCAT + c0 + fg);
    uint4 v0 = src[0], v1 = src[1];
    unsigned short tmp[16];
    *reinterpret_cast<uint4*>(tmp) = v0;
    *reinterpret_cast<uint4*>(tmp + 8) = v1;
#pragma unroll
    for (int j = 0; j < 16; j++) T[fg + j][nl] = tmp[j];
  }
  __syncthreads();
  {
    int f = tid >> 2, ng = (tid & 3) * 16;
    unsigned short tmp[16];
#pragma unroll
    for (int j = 0; j < 16; j++) tmp[j] = T[f][ng + j];
    uint4* dst = reinterpret_cast<uint4*>(
        Et + ((size_t)b * DD + f) * NTOT + r0 + ng);
    dst[0] = *reinterpret_cast<uint4*>(tmp);
    dst[1] = *reinterpret_cast<uint4*>(tmp + 8);
  }
}

// ---- side partial = A[m,krange] @ E : MFMA, Et staged via LDS ----
// kz=2 K-split (halves sp round-trip vs kz=4). 64-row M-tile, grid
// 48x2x8 = 768 blocks = 3/CU. CONV=1: read adj fp32, convert (RNE)
// in-register, use + write adjb bf16. CONV=0: read adjb bf16.
// A fragments register-prefetched one c-iteration ahead.
template <int CONV>
__global__ __launch_bounds__(256) void side_mfma_t(
    const float* __restrict__ adj, unsigned short* __restrict__ adjb,
    const unsigned short* __restrict__ Et, float* __restrict__ sp) {
  __shared__ __align__(16) unsigned short Bs[2][64][68];
  const int tid = threadIdx.x;
  const int w = tid >> 6, l = tid & 63;
  const int lane15 = l & 15, quad = l >> 4;
  const int b = blockIdx.z, kz = blockIdx.y;
  const int m0 = blockIdx.x * 64 + w * 16;
  const int kbase = kz * 1536;
  const size_t rowoff = (size_t)b * NTOT * NTOT +
                        (size_t)(m0 + lane15) * NTOT + kbase + quad * 8;
  const float* A32 = adj + rowoff;
  const unsigned short* A16 = adjb + rowoff;
  unsigned short* Aw = adjb + rowoff;

  const int sf = tid >> 3, ss = (tid & 7) * 8;
  const unsigned short* Eb = Et + (size_t)b * DD * NTOT + kbase;
  uint4 p0 = *reinterpret_cast<const uint4*>(Eb + (size_t)sf * NTOT + ss);
  uint4 p1 = *reinterpret_cast<const uint4*>(Eb + (size_t)(sf + 32) * NTOT + ss);

  bf16x8 a0, a1;
  float4 f0, f1, f2, f3;
  if (CONV) {
    f0 = *reinterpret_cast<const float4*>(A32 + 0);
    f1 = *reinterpret_cast<const float4*>(A32 + 4);
    f2 = *reinterpret_cast<const float4*>(A32 + 32);
    f3 = *reinterpret_cast<const float4*>(A32 + 36);
  } else {
    a0 = *reinterpret_cast<const bf16x8*>(A16);
    a1 = *reinterpret_cast<const bf16x8*>(A16 + 32);
  }

  f32x4 acc[4];
#pragma unroll
  for (int t = 0; t < 4; t++) acc[t] = (f32x4){0.f, 0.f, 0.f, 0.f};

  for (int c = 0; c < 24; c++) {
    const int buf = c & 1;
    __syncthreads();
    *reinterpret_cast<uint4*>(&Bs[buf][sf][ss]) = p0;
    *reinterpret_cast<uint4*>(&Bs[buf][sf + 32][ss]) = p1;
    __syncthreads();

    if (CONV) {
      uint4 u0 = pack8(f0, f1), u1 = pack8(f2, f3);
      *reinterpret_cast<uint4*>(Aw + c * 64) = u0;
      *reinterpret_cast<uint4*>(Aw + c * 64 + 32) = u1;
      a0 = u4_to_bf(u0);
      a1 = u4_to_bf(u1);
    }

    bf16x8 na0, na1;
    if (c + 1 < 24) {
      p0 = *reinterpret_cast<const uint4*>(Eb + (size_t)sf * NTOT + (c + 1) * 64 + ss);
      p1 = *reinterpret_cast<const uint4*>(Eb + (size_t)(sf + 32) * NTOT + (c + 1) * 64 + ss);
      if (CONV) {
        f0 = *reinterpret_cast<const float4*>(A32 + (c + 1) * 64);
        f1 = *reinterpret_cast<const float4*>(A32 + (c + 1) * 64 + 4);
        f2 = *reinterpret_cast<const float4*>(A32 + (c + 1) * 64 + 32);
        f3 = *reinterpret_cast<const float4*>(A32 + (c + 1) * 64 + 36);
      } else {
        na0 = *reinterpret_cast<const bf16x8*>(A16 + (c + 1) * 64);
        na1 = *reinterpret_cast<const bf16x8*>(A16 + (c + 1) * 64 + 32);
      }
    }

#pragma unroll
    for (int t = 0; t < 4; t++) {
      bf16x8 b0 = *reinterpret_cast<const bf16x8*>(&Bs[buf][t * 16 + lane15][quad * 8]);
      acc[t] = __builtin_amdgcn_mfma_f32_16x16x32_bf16(a0, b0, acc[t], 0, 0, 0);
    }
#pragma unroll
    for (int t = 0; t < 4; t++) {
      bf16x8 b1 = *reinterpret_cast<const bf16x8*>(&Bs[buf][t * 16 + lane15][32 + quad * 8]);
      acc[t] = __builtin_amdgcn_mfma_f32_16x16x32_bf16(a1, b1, acc[t], 0, 0, 0);
    }
    if (!CONV && (c + 1 < 24)) { a0 = na0; a1 = na1; }
  }

  float* S = sp + ((size_t)kz * BB + b) * ((size_t)NTOT * DD);
#pragma unroll
  for (int t = 0; t < 4; t++)
#pragma unroll
    for (int r = 0; r < 4; r++)
      S[(size_t)(m0 + quad * 4 + r) * DD + t * 16 + lane15] = acc[t][r];
}

// ---- ego_out = lrelu(side@gcW^T+gcb) + lrelu((ego*side)@biW^T+bib), bf16 io ----
// 16 rows per block (4 rows per wave-thread): weight staging amortized 4x,
// wG/wB loaded once per k for 4 row-FMAs.
__global__ __launch_bounds__(256) void layer_post(
    const float* __restrict__ sp, unsigned short* __restrict__ ecat, int cin,
    const float* __restrict__ wTg, const float* __restrict__ wTb,
    const float* __restrict__ gcb, const float* __restrict__ bib) {
  __shared__ float wG[4096];
  __shared__ float wB[4096];
  __shared__ float rowS[16][64];
  __shared__ float rowE[16][64];
  const int tid = threadIdx.x;
#pragma unroll
  for (int i = 0; i < 16; i++) {
    int idx = tid + i * 256;
    wG[idx] = wTg[idx];   // already [k][d]
    wB[idx] = wTb[idx];
  }
  const int wv = tid >> 6, lane = tid & 63;
  const size_t base = (size_t)blockIdx.x * 16;
  const size_t P = (size_t)BB * NTOT * DD;
#pragma unroll
  for (int rr = 0; rr < 4; rr++) {
    const size_t row = base + wv * 4 + rr;
    const size_t off = row * DD + lane;
    rowS[wv * 4 + rr][lane] = sp[off] + sp[P + off];
    rowE[wv * 4 + rr][lane] = bf2f(ecat[row * KCAT + cin + lane]);
  }
  __syncthreads();
  float sacc[4], bacc[4];
#pragma unroll
  for (int rr = 0; rr < 4; rr++) { sacc[rr] = gcb[lane]; bacc[rr] = bib[lane]; }
#pragma unroll 8
  for (int k = 0; k < 64; k++) {
    float wg = wG[k * 64 + lane];
    float wb = wB[k * 64 + lane];
#pragma unroll
    for (int rr = 0; rr < 4; rr++) {
      float sk = rowS[wv * 4 + rr][k];
      float ek = rowE[wv * 4 + rr][k];
      sacc[rr] += sk * wg;
      bacc[rr] += (ek * sk) * wb;
    }
  }
#pragma unroll
  for (int rr = 0; rr < 4; rr++) {
    float s  = sacc[rr] > 0.f ? sacc[rr] : 0.01f * sacc[rr];
    float bi = bacc[rr] > 0.f ? bacc[rr] : 0.01f * bacc[rr];
    const size_t row = base + wv * 4 + rr;
    ecat[row * KCAT + cin + 64 + lane] = f2bf(s + bi);
  }
}

// ---- scores = U @ I^T over K=192, LDS-staged tiles, XOR-swizzled chunks ----
__global__ __launch_bounds__(256) void scores_mfma(
    const unsigned short* __restrict__ ecat, float* __restrict__ out) {
  __shared__ __align__(16) unsigned short Ut[64 * KCAT];
  __shared__ __align__(16) unsigned short It[64 * KCAT];
  const int tid = threadIdx.x;
  const int w = tid >> 6, l = tid & 63;
  const int lane15 = l & 15, quad = l >> 4;
  const int b = blockIdx.z;
  const int u0 = blockIdx.y * 64;
  const int i0 = blockIdx.x * 64;
#pragma unroll
  for (int it = 0; it < 6; it++) {
    int idx = tid + it * 256;
    int row = idx / 24, c = idx - row * 24;
    int cs = c ^ (row & 7);
    uint4 vu = reinterpret_cast<const uint4*>(
        ecat + ((size_t)b * NTOT + u0 + row) * KCAT)[c];
    uint4 vi = reinterpret_cast<const uint4*>(
        ecat + ((size_t)b * NTOT + NUU + i0 + row) * KCAT)[c];
    reinterpret_cast<uint4*>(Ut)[row * 24 + cs] = vu;
    reinterpret_cast<uint4*>(It)[row * 24 + cs] = vi;
  }
  __syncthreads();
  f32x4 acc[4];
#pragma unroll
  for (int t = 0; t < 4; t++) acc[t] = (f32x4){0.f, 0.f, 0.f, 0.f};
  const int urow = w * 16 + lane15;
#pragma unroll
  for (int ks = 0; ks < 6; ks++) {
    int cu = (ks * 4 + quad) ^ (urow & 7);
    bf16x8 af = reinterpret_cast<const bf16x8*>(Ut)[urow * 24 + cu];
#pragma unroll
    for (int t = 0; t < 4; t++) {
      int irow = t * 16 + lane15;
      int ci = (ks * 4 + quad) ^ (irow & 7);
      bf16x8 bf = reinterpret_cast<const bf16x8*>(It)[irow * 24 + ci];
      acc[t] = __builtin_amdgcn_mfma_f32_16x16x32_bf16(af, bf, acc[t], 0, 0, 0);
    }
  }
  float* O = out + (size_t)b * NUU * NII;
#pragma unroll
  for (int t = 0; t < 4; t++)
#pragma unroll
    for (int r = 0; r < 4; r++)
      O[(size_t)(u0 + w * 16 + quad * 4 + r) * NII + i0 + t * 16 + lane15] =
          acc[t][r];
}

// ---- in-place row log_softmax over 2048 ----
__global__ __launch_bounds__(256) void logsoftmax_kernel(float* __restrict__ out) {
  __shared__ float rm[4];
  __shared__ float rs[4];
  const int tid = threadIdx.x;
  const int lane = tid & 63, wv = tid >> 6;
  float* row = out + (size_t)blockIdx.x * NII;
  float4 v0 = *reinterpret_cast<const float4*>(row + tid * 4);
  float4 v1 = *reinterpret_cast<const float4*>(row + 1024 + tid * 4);
  float m = fmaxf(fmaxf(fmaxf(v0.x, v0.y), fmaxf(v0.z, v0.w)),
                  fmaxf(fmaxf(v1.x, v1.y), fmaxf(v1.z, v1.w)));
#pragma unroll
  for (int off = 32; off > 0; off >>= 1) m = fmaxf(m, __shfl_xor(m, off));
  if (lane == 0) rm[wv] = m;
  __syncthreads();
  m = fmaxf(fmaxf(rm[0], rm[1]), fmaxf(rm[2], rm[3]));
  float s = expf(v0.x - m) + expf(v0.y - m) + expf(v0.z - m) + expf(v0.w - m) +
            expf(v1.x - m) + expf(v1.y - m) + expf(v1.z - m) + expf(v1.w - m);
#pragma unroll
  for (int off = 32; off > 0; off >>= 1) s += __shfl_xor(s, off);
  if (lane == 0) rs[wv] = s;
  __syncthreads();
  float lse = m + logf(rs[0] + rs[1] + rs[2] + rs[3]);
  v0.x -= lse; v0.y -= lse; v0.z -= lse; v0.w -= lse;
  v1.x -= lse; v1.y -= lse; v1.z -= lse; v1.w -= lse;
  *reinterpret_cast<float4*>(row + tid * 4) = v0;
  *reinterpret_cast<float4*>(row + 1024 + tid * 4) = v1;
}

extern "C" void kernel_launch(void* const* d_in, const int* in_sizes, int n_in,
                              void* d_out, int out_size, void* d_ws, size_t ws_size,
                              hipStream_t stream) {
  (void)in_sizes; (void)n_in; (void)out_size; (void)ws_size;
  const int*   uidx = (const int*)d_in[0];
  const int*   iidx = (const int*)d_in[1];
  const float* adj  = (const float*)d_in[2];
  const float* utab = (const float*)d_in[3];
  const float* itab = (const float*)d_in[4];
  const float* gcw  = (const float*)d_in[5];
  const float* gcb  = (const float*)d_in[6];
  const float* biw  = (const float*)d_in[7];
  const float* bib  = (const float*)d_in[8];
  float* out = (float*)d_out;

  // ws layout: ecat bf16 [B][3072][192] (9.4MB) | Et bf16 [B][64][3072] (3.1MB)
  //          | adjb bf16 [B][3072][3072] (151MB, written by side_mfma_t<1>)
  unsigned short* ecat = (unsigned short*)d_ws;
  unsigned short* Et   = ecat + (size_t)BB * NTOT * KCAT;
  unsigned short* adjb = Et + (size_t)BB * DD * NTOT;
  // d_out scratch: sp = 2 K-split fp32 partials [2][B][3072][64] (12.6MB),
  // then wT = transposed weights [4][64][64] (64KB). Both consumed by
  // layer_post before scores_mfma overwrites d_out.
  float* sp = (float*)d_out;
  const size_t P = (size_t)BB * NTOT * DD;
  float* wT = (float*)d_out + 2 * P;

  gather_t<<<dim3(385), 256, 0, stream>>>(uidx, iidx, utab, itab, gcw, biw, ecat, Et, wT);
  side_mfma_t<1><<<dim3(48, 2, BB), 256, 0, stream>>>(adj, adjb, Et, sp);
  layer_post<<<dim3(BB * NTOT / 16), 256, 0, stream>>>(sp, ecat, 0, wT, wT + 2 * 4096, gcb, bib);
  conv_t<<<dim3(48, BB), 256, 0, stream>>>(ecat, 64, Et);
  side_mfma_t<0><<<dim3(48, 2, BB), 256, 0, stream>>>(adj, adjb, Et, sp);
  layer_post<<<dim3(BB * NTOT / 16), 256, 0, stream>>>(sp, ecat, 64, wT + 4096, wT + 3 * 4096, gcb + 64, bib + 64);
  scores_mfma<<<dim3(32, 16, BB), 256, 0, stream>>>(ecat, out);
  logsoftmax_kernel<<<dim3(BB * NUU), 256, 0, stream>>>(out);
}